// Round 3
// baseline (53.195 us; speedup 1.0000x reference)
//
#include <hip/hip_runtime.h>

#define NB 1024          // B
#define LSZ 128          // L
#define PTS_FLOATS (NB * 3 * LSZ * LSZ)     // 50,331,648
#define PTS4 (PTS_FLOATS / 4)               // 12,582,912 float4
#define PH4_PER_B (LSZ * LSZ / 4)           // 4096 float4 per b (real part only)

// One block per b. No workspace. Every thread redundantly computes the
// Rodrigues matrix (reference f32 op order), then streams float4 stores.
// Output layout (float32): [pts_rot (1024,3,16384)] ++ [Re(phase) (1024,128,128)]
__global__ __launch_bounds__(256) void pose_fused_kernel(
    const float* __restrict__ rotvec,
    const float* __restrict__ offs,
    const int* __restrict__ index,
    float* __restrict__ out,
    int out_n4) {
    const float PI_F   = (float)3.14159265358979323846;   // fl32(pi)
    const float TWO_PI = (float)6.28318530717958647692;   // fl32(2*pi)
    const float CPS    = (float)0.04908738521234052;      // fl32(2*pi/128)

    int b  = blockIdx.x;
    int id = index[b];
    float rx = rotvec[id * 3 + 0];
    float ry = rotvec[id * 3 + 1];
    float rz = rotvec[id * 3 + 2];
    // theta = ||r||, sum order ((x^2+y^2)+z^2), all f32, no fma contraction
    float theta = sqrtf(__fadd_rn(__fadd_rn(__fmul_rn(rx, rx), __fmul_rn(ry, ry)),
                                  __fmul_rn(rz, rz)));
    float denom = __fadd_rn(theta, 1e-6f);
    float kx = __fdiv_rn(rx, denom);
    float ky = __fdiv_rn(ry, denom);
    float kz = __fdiv_rn(rz, denom);
    float s  = sinf(theta);
    float c1 = __fsub_rn(1.0f, cosf(theta));
    float kx2 = __fmul_rn(kx, kx), ky2 = __fmul_rn(ky, ky), kz2 = __fmul_rn(kz, kz);
    float kxky = __fmul_rn(kx, ky), kxkz = __fmul_rn(kx, kz), kykz = __fmul_rn(ky, kz);
    // (K@K) cols 0,1 (zero terms drop exactly in the matmul sum)
    float K2_00 = __fadd_rn(-kz2, -ky2);
    float K2_10 = kxky;
    float K2_20 = kxkz;
    float K2_01 = kxky;
    float K2_11 = __fadd_rn(-kz2, -kx2);
    float K2_21 = kykz;
    // R = (eye + s*K) + c1*(K@K)
    float R00 = __fadd_rn(1.0f, __fmul_rn(c1, K2_00));
    float R10 = __fadd_rn(__fmul_rn(s, kz),  __fmul_rn(c1, K2_10));
    float R20 = __fadd_rn(__fmul_rn(s, -ky), __fmul_rn(c1, K2_20));
    float R01 = __fadd_rn(__fmul_rn(s, -kz), __fmul_rn(c1, K2_01));
    float R11 = __fadd_rn(1.0f, __fmul_rn(c1, K2_11));
    float R21 = __fadd_rn(__fmul_rn(s, kx),  __fmul_rn(c1, K2_21));
    // Row-reversed coefficient pairs: out row i uses R row (2-i), cols 0(x),1(y)
    float A0 = R20, C0 = R21;   // i = 0
    float A1 = R10, C1 = R11;   // i = 1
    float A2 = R00, C2 = R01;   // i = 2
    float off0 = -offs[id * 2 + 0];
    float off1 = -offs[id * 2 + 1];

    // ---- pts_rot region: 3 slices x 4096 float4, contiguous per (b,i) ----
#pragma unroll
    for (int i = 0; i < 3; ++i) {
        float a = (i == 0) ? A0 : (i == 1) ? A1 : A2;
        float c = (i == 0) ? C0 : (i == 1) ? C1 : C2;
        int base4 = (b * 3 + i) * 4096;
        for (int k4 = threadIdx.x; k4 < 4096; k4 += 256) {
            int k0  = k4 << 2;
            int row = k0 >> 7;                       // 4 consecutive never cross a row
            float y  = __fmul_rn(PI_F, (float)(row - 64) * 0.015625f);
            float cy = __fmul_rn(c, y);
            float4 o;
            float* op = &o.x;
#pragma unroll
            for (int q = 0; q < 4; ++q) {
                int col = ((k0 + q) & 127) - 64;
                float x = __fmul_rn(PI_F, (float)col * 0.015625f);
                float v = __fadd_rn(__fmul_rn(a, x), cy);  // R0*x + R1*y (+0)
                float w = __fadd_rn(v, PI_F);
                float r = fmodf(w, TWO_PI);                // exact remainder
                if (r < 0.0f) r = __fadd_rn(r, TWO_PI);    // numpy floor-mod
                op[q] = __fsub_rn(r, PI_F);
            }
            int f4 = base4 + k4;
            if (f4 < out_n4) reinterpret_cast<float4*>(out)[f4] = o;
        }
    }

    // ---- phase region: Re(exp(i*arg)) = cos(arg), 4096 float4 per b ----
    int baseg = PTS4 + b * PH4_PER_B;
    for (int g = threadIdx.x; g < PH4_PER_B; g += 256) {
        int i  = g >> 5;            // row 0..127
        int j0 = (g & 31) << 2;     // starting column of this float4
        float g2i = __fmul_rn(CPS, (float)(i - 64));
        float t2  = __fmul_rn(g2i, off1);
        float4 o;
        float* op = &o.x;
#pragma unroll
        for (int q = 0; q < 4; ++q) {
            int j = j0 + q;
            float g2j = __fmul_rn(CPS, (float)(j - 64));
            float arg = __fadd_rn(__fmul_rn(g2j, off0), t2);
            op[q] = cosf(arg);
        }
        int f4 = baseg + g;
        if (f4 < out_n4) reinterpret_cast<float4*>(out)[f4] = o;
    }
}

extern "C" void kernel_launch(void* const* d_in, const int* in_sizes, int n_in,
                              void* d_out, int out_size, void* d_ws, size_t ws_size,
                              hipStream_t stream) {
    const float* rotvec = (const float*)d_in[0];
    const float* offs   = (const float*)d_in[1];
    const int*   index  = (const int*)d_in[2];
    float* out = (float*)d_out;
    int out_n4 = out_size / 4;   // float4 capacity of d_out

    pose_fused_kernel<<<NB, 256, 0, stream>>>(rotvec, offs, index, out, out_n4);
}

// Round 4
// 46.640 us; speedup vs baseline: 1.1405x; 1.1405x over previous
//
#include <hip/hip_runtime.h>

#define NB 1024          // B
#define LSZ 128          // L
#define PTS_FLOATS (NB * 3 * LSZ * LSZ)     // 50,331,648
#define PTS4 (PTS_FLOATS / 4)               // 12,582,912 float4
#define PH4_PER_B (LSZ * LSZ / 4)           // 4096 float4 per b (real part only)

// One block per b. No workspace. Every thread redundantly computes the
// Rodrigues matrix (reference f32 op order), then streams float4 stores.
// Output layout (float32): [pts_rot (1024,3,16384)] ++ [Re(phase) (1024,128,128)]
//
// mod(w, 2pi) for w in (-2pi, 2*2pi) is replaced by two conditional ops,
// bit-identical to numpy's fmod+adjust in that range (see round-3 analysis:
// w - fl(2pi) is exactly representable for w in [2pi, 2*2pi); numpy's
// negative-branch add is the same fl(w + 2pi) we compute).
__global__ __launch_bounds__(256) void pose_fused_kernel(
    const float* __restrict__ rotvec,
    const float* __restrict__ offs,
    const int* __restrict__ index,
    float* __restrict__ out,
    int out_n4) {
    const float PI_F   = (float)3.14159265358979323846;   // fl32(pi)
    const float TWO_PI = (float)6.28318530717958647692;   // fl32(2*pi)
    const float CPS    = (float)0.04908738521234052;      // fl32(2*pi/128)

    int b  = blockIdx.x;
    int id = index[b];
    float rx = rotvec[id * 3 + 0];
    float ry = rotvec[id * 3 + 1];
    float rz = rotvec[id * 3 + 2];
    // theta = ||r||, sum order ((x^2+y^2)+z^2), all f32, no fma contraction
    float theta = sqrtf(__fadd_rn(__fadd_rn(__fmul_rn(rx, rx), __fmul_rn(ry, ry)),
                                  __fmul_rn(rz, rz)));
    float denom = __fadd_rn(theta, 1e-6f);
    float kx = __fdiv_rn(rx, denom);
    float ky = __fdiv_rn(ry, denom);
    float kz = __fdiv_rn(rz, denom);
    float s  = sinf(theta);
    float c1 = __fsub_rn(1.0f, cosf(theta));
    float kx2 = __fmul_rn(kx, kx), ky2 = __fmul_rn(ky, ky), kz2 = __fmul_rn(kz, kz);
    float kxky = __fmul_rn(kx, ky), kxkz = __fmul_rn(kx, kz), kykz = __fmul_rn(ky, kz);
    // (K@K) cols 0,1 (zero terms drop exactly in the matmul sum)
    float K2_00 = __fadd_rn(-kz2, -ky2);
    float K2_10 = kxky;
    float K2_20 = kxkz;
    float K2_01 = kxky;
    float K2_11 = __fadd_rn(-kz2, -kx2);
    float K2_21 = kykz;
    // R = (eye + s*K) + c1*(K@K)
    float R00 = __fadd_rn(1.0f, __fmul_rn(c1, K2_00));
    float R10 = __fadd_rn(__fmul_rn(s, kz),  __fmul_rn(c1, K2_10));
    float R20 = __fadd_rn(__fmul_rn(s, -ky), __fmul_rn(c1, K2_20));
    float R01 = __fadd_rn(__fmul_rn(s, -kz), __fmul_rn(c1, K2_01));
    float R11 = __fadd_rn(1.0f, __fmul_rn(c1, K2_11));
    float R21 = __fadd_rn(__fmul_rn(s, kx),  __fmul_rn(c1, K2_21));
    // Row-reversed coefficient pairs: out row i uses R row (2-i), cols 0(x),1(y)
    float A0 = R20, C0 = R21;   // i = 0
    float A1 = R10, C1 = R11;   // i = 1
    float A2 = R00, C2 = R01;   // i = 2
    float off0 = -offs[id * 2 + 0];
    float off1 = -offs[id * 2 + 1];

    // ---- pts_rot region: 3 slices x 4096 float4, contiguous per (b,i) ----
#pragma unroll
    for (int i = 0; i < 3; ++i) {
        float a = (i == 0) ? A0 : (i == 1) ? A1 : A2;
        float c = (i == 0) ? C0 : (i == 1) ? C1 : C2;
        int base4 = (b * 3 + i) * 4096;
        for (int k4 = threadIdx.x; k4 < 4096; k4 += 256) {
            int k0  = k4 << 2;
            int row = k0 >> 7;                       // 4 consecutive never cross a row
            float y  = __fmul_rn(PI_F, (float)(row - 64) * 0.015625f);
            float cy = __fmul_rn(c, y);
            float4 o;
            float* op = &o.x;
#pragma unroll
            for (int q = 0; q < 4; ++q) {
                int col = ((k0 + q) & 127) - 64;
                float x = __fmul_rn(PI_F, (float)col * 0.015625f);
                float v = __fadd_rn(__fmul_rn(a, x), cy);  // R0*x + R1*y (+0)
                float w = __fadd_rn(v, PI_F);
                // exact mod(w, 2pi) for w in (-2pi, 2*2pi)
                float r = (w >= TWO_PI) ? __fsub_rn(w, TWO_PI) : w;
                r = (r < 0.0f) ? __fadd_rn(r, TWO_PI) : r;
                op[q] = __fsub_rn(r, PI_F);
            }
            int f4 = base4 + k4;
            if (f4 < out_n4) reinterpret_cast<float4*>(out)[f4] = o;
        }
    }

    // ---- phase region: Re(exp(i*arg)) = cos(arg), 4096 float4 per b ----
    int baseg = PTS4 + b * PH4_PER_B;
    for (int g = threadIdx.x; g < PH4_PER_B; g += 256) {
        int i  = g >> 5;            // row 0..127
        int j0 = (g & 31) << 2;     // starting column of this float4
        float g2i = __fmul_rn(CPS, (float)(i - 64));
        float t2  = __fmul_rn(g2i, off1);
        float4 o;
        float* op = &o.x;
#pragma unroll
        for (int q = 0; q < 4; ++q) {
            int j = j0 + q;
            float g2j = __fmul_rn(CPS, (float)(j - 64));
            float arg = __fadd_rn(__fmul_rn(g2j, off0), t2);
            op[q] = __cosf(arg);   // v_cos_f32 path; err ~1e-5 << 0.0628 threshold
        }
        int f4 = baseg + g;
        if (f4 < out_n4) reinterpret_cast<float4*>(out)[f4] = o;
    }
}

extern "C" void kernel_launch(void* const* d_in, const int* in_sizes, int n_in,
                              void* d_out, int out_size, void* d_ws, size_t ws_size,
                              hipStream_t stream) {
    const float* rotvec = (const float*)d_in[0];
    const float* offs   = (const float*)d_in[1];
    const int*   index  = (const int*)d_in[2];
    float* out = (float*)d_out;
    int out_n4 = out_size / 4;   // float4 capacity of d_out

    pose_fused_kernel<<<NB, 256, 0, stream>>>(rotvec, offs, index, out, out_n4);
}

// Round 6
// 45.590 us; speedup vs baseline: 1.1668x; 1.0230x over previous
//
#include <hip/hip_runtime.h>

#define NB 1024          // B
#define LSZ 128          // L
#define PTS_FLOATS (NB * 3 * LSZ * LSZ)     // 50,331,648
#define PTS4 (PTS_FLOATS / 4)               // 12,582,912 float4
#define NBLK_PTS (NB * 3)                   // 3072 pts blocks (one per (b,i) slice)
#define NBLK_ALL (NBLK_PTS + NB)            // + 1024 phase blocks

// Split grid. pts blocks use the EXACT per-element statement structure of the
// round-4 PASSING kernel (single-use mul chain -> same fma contraction ->
// same last-ulp rounding at mod-2pi wrap boundaries). Do NOT hoist a*x into
// a multi-use temp: that changed contraction and flipped a wrap (round 5).
__global__ __launch_bounds__(256) void pose_split_kernel(
    const float* __restrict__ rotvec,
    const float* __restrict__ offs,
    const int* __restrict__ index,
    float* __restrict__ out,
    int out_n4) {
    const float PI_F   = (float)3.14159265358979323846;   // fl32(pi)
    const float TWO_PI = (float)6.28318530717958647692;   // fl32(2*pi)
    const float CPS    = (float)0.04908738521234052;      // fl32(2*pi/128)

    int t   = blockIdx.x;
    int tid = threadIdx.x;

    if (t < NBLK_PTS) {
        int b = (int)((unsigned)t / 3u);
        int i = t - b * 3;
        int id = index[b];
        float rx = rotvec[id * 3 + 0];
        float ry = rotvec[id * 3 + 1];
        float rz = rotvec[id * 3 + 2];
        // theta = ||r||, sum order ((x^2+y^2)+z^2), all f32
        float theta = sqrtf(__fadd_rn(__fadd_rn(__fmul_rn(rx, rx), __fmul_rn(ry, ry)),
                                      __fmul_rn(rz, rz)));
        float denom = __fadd_rn(theta, 1e-6f);
        float kx = __fdiv_rn(rx, denom);
        float ky = __fdiv_rn(ry, denom);
        float kz = __fdiv_rn(rz, denom);
        float s  = sinf(theta);
        float c1 = __fsub_rn(1.0f, cosf(theta));
        float kx2 = __fmul_rn(kx, kx), ky2 = __fmul_rn(ky, ky), kz2 = __fmul_rn(kz, kz);
        float kxky = __fmul_rn(kx, ky), kxkz = __fmul_rn(kx, kz), kykz = __fmul_rn(ky, kz);
        float K2_00 = __fadd_rn(-kz2, -ky2);
        float K2_10 = kxky;
        float K2_20 = kxkz;
        float K2_01 = kxky;
        float K2_11 = __fadd_rn(-kz2, -kx2);
        float K2_21 = kykz;
        float R00 = __fadd_rn(1.0f, __fmul_rn(c1, K2_00));
        float R10 = __fadd_rn(__fmul_rn(s, kz),  __fmul_rn(c1, K2_10));
        float R20 = __fadd_rn(__fmul_rn(s, -ky), __fmul_rn(c1, K2_20));
        float R01 = __fadd_rn(__fmul_rn(s, -kz), __fmul_rn(c1, K2_01));
        float R11 = __fadd_rn(1.0f, __fmul_rn(c1, K2_11));
        float R21 = __fadd_rn(__fmul_rn(s, kx),  __fmul_rn(c1, K2_21));
        // Row reversal: slice i uses R row (2-i), cols 0 (x) and 1 (y)
        float a = (i == 0) ? R20 : (i == 1) ? R10 : R00;
        float c = (i == 0) ? R21 : (i == 1) ? R11 : R01;

        int base4 = t * 4096;    // == (b*3+i)*4096
        // EXACT round-4 inner loop body (statement-for-statement).
        for (int k4 = tid; k4 < 4096; k4 += 256) {
            int k0  = k4 << 2;
            int row = k0 >> 7;                       // 4 consecutive never cross a row
            float y  = __fmul_rn(PI_F, (float)(row - 64) * 0.015625f);
            float cy = __fmul_rn(c, y);
            float4 o;
            float* op = &o.x;
#pragma unroll
            for (int q = 0; q < 4; ++q) {
                int col = ((k0 + q) & 127) - 64;
                float x = __fmul_rn(PI_F, (float)col * 0.015625f);
                float v = __fadd_rn(__fmul_rn(a, x), cy);  // single-use mul chain
                float w = __fadd_rn(v, PI_F);
                // exact mod(w, 2pi) for w in (-2pi, 2*2pi)
                float r = (w >= TWO_PI) ? __fsub_rn(w, TWO_PI) : w;
                r = (r < 0.0f) ? __fadd_rn(r, TWO_PI) : r;
                op[q] = __fsub_rn(r, PI_F);
            }
            int f4 = base4 + k4;
            if (f4 < out_n4) reinterpret_cast<float4*>(out)[f4] = o;
        }
    } else {
        int b  = t - NBLK_PTS;
        int id = index[b];
        float off0 = -offs[id * 2 + 0];
        float off1 = -offs[id * 2 + 1];

        // Hoist is SAFE here: cos is continuous, ~1e-5 rad arg perturbation
        // cannot cross any cliff (threshold 0.0628).
        int j0 = (tid & 31) << 2;
        float bx[4];
#pragma unroll
        for (int q = 0; q < 4; ++q) {
            float g2j = __fmul_rn(CPS, (float)(j0 + q - 64));
            bx[q] = __fmul_rn(g2j, off0);
        }

        int baseg = PTS4 + b * 4096;
        for (int g = tid; g < 4096; g += 256) {
            int i = g >> 5;            // row 0..127
            float g2i = __fmul_rn(CPS, (float)(i - 64));
            float t2  = __fmul_rn(g2i, off1);
            float4 o;
            float* op = &o.x;
#pragma unroll
            for (int q = 0; q < 4; ++q) {
                float arg = __fadd_rn(bx[q], t2);
                op[q] = __cosf(arg);   // v_cos_f32 path; err ~1e-5 << threshold
            }
            int f4 = baseg + g;
            if (f4 < out_n4) reinterpret_cast<float4*>(out)[f4] = o;
        }
    }
}

extern "C" void kernel_launch(void* const* d_in, const int* in_sizes, int n_in,
                              void* d_out, int out_size, void* d_ws, size_t ws_size,
                              hipStream_t stream) {
    const float* rotvec = (const float*)d_in[0];
    const float* offs   = (const float*)d_in[1];
    const int*   index  = (const int*)d_in[2];
    float* out = (float*)d_out;
    int out_n4 = out_size / 4;   // float4 capacity of d_out

    pose_split_kernel<<<NBLK_ALL, 256, 0, stream>>>(rotvec, offs, index, out, out_n4);
}